// Round 4
// baseline (107.118 us; speedup 1.0000x reference)
//
#include <hip/hip_runtime.h>
#include <hip/hip_bf16.h>

// B=8, T=2048, E=1024, H=64
// Round 4: fix the L2-thrash found in round 3 (FETCH=45MB = 8 XCDs x full
// qkv; 6MB working set > 4MB per-XCD L2).
//  - attn blocks decoded XCD-aware from a 1-D grid: xcd=id%8 owns a fixed
//    PAIR of s-chunks -> per-XCD set = qb(2MB)+KV slices(0.5MB) < 4MB L2.
//  - staging of step i+1 issued at TOP of step i (overlaps whole compute);
//    single __syncthreads per step (its vmcnt(0) is ~free: Q-load waits
//    inside QK already retired the stage loads, vmcnt is in-order).
//  - non-temporal for streamed partial buffer and x.
// Workspace: qb 2MB | kb 2MB | vtb 2MB | partial 32MB bf16

typedef __attribute__((ext_vector_type(4))) float f32x4;
typedef __attribute__((ext_vector_type(4))) float float4_t;
typedef __attribute__((ext_vector_type(8))) short short8;
typedef __attribute__((ext_vector_type(4))) unsigned uint4_t;
typedef __attribute__((ext_vector_type(2))) unsigned uint2_t;

#define MFMA16(a, b, c) __builtin_amdgcn_mfma_f32_16x16x32_bf16(a, b, c, 0, 0, 0)

__device__ __forceinline__ short f2bf(float f) {
  unsigned u = __builtin_bit_cast(unsigned, f);
  unsigned r = (u + 0x7FFFu + ((u >> 16) & 1u)) >> 16;  // RNE
  return (short)r;
}

__device__ __forceinline__ unsigned cvt_pk_bf16(float lo, float hi) {
  unsigned r;
  asm volatile("v_cvt_pk_bf16_f32 %0, %1, %2" : "=v"(r) : "v"(lo), "v"(hi));
  return r;
}

__device__ __forceinline__ void gload16(const short* g, short* l) {
  __builtin_amdgcn_global_load_lds(
      (const __attribute__((address_space(1))) unsigned*)g,
      (__attribute__((address_space(3))) unsigned*)l, 16, 0, 0);
}

// ---------------- Kernel 1: merged QKV projection ----------------
//  qb: idx = (((b*128 + t>>4)*2 + d>>5)*64 + lane)*8 + (d&7),  lane=(((d>>3)&3)<<4)|(t&15)
//  kb: idx = ((((b*64 + s>>5)*2 + (s>>4)&1)*2 + d>>5)*64 + lane)*8 + (d&7)
//  vtb:idx = (((b*4 + d>>4)*64 + s>>5)*64 + lane)*8 + j, lane=(((s>>2)&3)<<4)|(d&15),
//            j = (s&3) + ((s>>4)&1)*4
__global__ __launch_bounds__(512) void proj_kernel(
    const float* __restrict__ x, const float* __restrict__ Wq,
    const float* __restrict__ Wk, const float* __restrict__ Wv,
    short* __restrict__ qb, short* __restrict__ kb, short* __restrict__ vtb) {
  __shared__ __align__(16) short lds_A[64 * 72];
  __shared__ __align__(16) short lds_W[3][64 * 72];
  const int tid = threadIdx.x;
  const int m0 = blockIdx.x * 64;
  const int l = tid & 63, w = tid >> 6;
  const int g = l >> 4, lr = l & 15;
  const int wr = w & 3, wc = w >> 2;

  f32x4 acc[6];
#pragma unroll
  for (int i = 0; i < 6; i++) acc[i] = (f32x4){0.f, 0.f, 0.f, 0.f};

  for (int k0 = 0; k0 < 1024; k0 += 64) {
    __syncthreads();
    {
      int row = tid >> 3;
      int k8 = (tid & 7) * 8;
      const float* src = x + (m0 + row) * 1024 + k0 + k8;
      float4_t f0 = __builtin_nontemporal_load((const float4_t*)src);
      float4_t f1 = __builtin_nontemporal_load((const float4_t*)(src + 4));
      short8 v;
      v[0] = f2bf(f0[0]); v[1] = f2bf(f0[1]); v[2] = f2bf(f0[2]); v[3] = f2bf(f0[3]);
      v[4] = f2bf(f1[0]); v[5] = f2bf(f1[1]); v[6] = f2bf(f1[2]); v[7] = f2bf(f1[3]);
      *(short8*)&lds_A[row * 72 + k8] = v;
    }
    {
      int n = tid & 63;
      int kk0 = (tid >> 6) * 8;
#pragma unroll
      for (int wi = 0; wi < 3; wi++) {
        const float* W = (wi == 0) ? Wq : (wi == 1) ? Wk : Wv;
        short8 tv;
#pragma unroll
        for (int i = 0; i < 8; i++) tv[i] = f2bf(W[(k0 + kk0 + i) * 64 + n]);
        *(short8*)&lds_W[wi][n * 72 + kk0] = tv;
      }
    }
    __syncthreads();
#pragma unroll
    for (int ks = 0; ks < 2; ks++) {
      short8 a = *(const short8*)&lds_A[(wr * 16 + lr) * 72 + ks * 32 + g * 8];
#pragma unroll
      for (int nf = 0; nf < 6; nf++) {
        int colg0 = wc * 96 + nf * 16;
        short8 bfrag = *(const short8*)&lds_W[colg0 >> 6][((colg0 & 63) + lr) * 72 + ks * 32 + g * 8];
        acc[nf] = MFMA16(a, bfrag, acc[nf]);
      }
    }
  }
#pragma unroll
  for (int nf = 0; nf < 6; nf++) {
    int colg0 = wc * 96 + nf * 16;
    int wi = colg0 >> 6;
    int d = (colg0 & 63) + lr;
    // fold 1/sqrt(H) * log2(e) into q so attn softmax uses 2^x directly
    float scale = (wi == 0) ? 0.18033688f : 1.0f;
#pragma unroll
    for (int r = 0; r < 4; r++) {
      int row = m0 + wr * 16 + g * 4 + r;
      int b = row >> 11, t = row & 2047;
      short bv = f2bf(acc[nf][r] * scale);
      if (wi == 0) {
        int idx = (((b * 128 + (t >> 4)) * 2 + (d >> 5)) * 64 +
                   ((((d >> 3) & 3) << 4) | (t & 15))) * 8 + (d & 7);
        qb[idx] = bv;
      } else if (wi == 1) {
        int idx = ((((b * 64 + (t >> 5)) * 2 + ((t >> 4) & 1)) * 2 + (d >> 5)) * 64 +
                   ((((d >> 3) & 3) << 4) | (t & 15))) * 8 + (d & 7);
        kb[idx] = bv;
      } else {
        int idx = (((b * 4 + (d >> 4)) * 64 + (t >> 5)) * 64 +
                   ((((t >> 2) & 3) << 4) | (d & 15))) * 8 +
                  ((t & 3) + (((t >> 4) & 1) << 2));
        vtb[idx] = bv;
      }
    }
  }
}

// ---------------- Kernel 2: pipelined fused attention ----------------
// LDS frags (512 shorts = 1KB each): f in [0,32) = K frag (b=f>>2, sf=(f>>1)&1,
// ks=f&1); f in [32,64) = V frag (fv=f-32: b=fv>>2, df=fv&3).
__device__ __forceinline__ void stage_step(const short* __restrict__ kb,
                                           const short* __restrict__ vtb,
                                           short* lds_buf, int w, int l, int sblk) {
  if (w < 4) {
#pragma unroll
    for (int i = 0; i < 8; i++) {
      int f = w * 8 + i;  // K frag
      const short* src = kb + (size_t)((f >> 2) * 256 + sblk * 4 + (f & 3)) * 512 + l * 8;
      gload16(src, lds_buf + f * 512);
    }
  } else {
#pragma unroll
    for (int i = 0; i < 8; i++) {
      int fv = (w - 4) * 8 + i;  // V frag
      const short* src = vtb + (size_t)(fv * 64 + sblk) * 512 + l * 8;
      gload16(src, lds_buf + (32 + fv) * 512);
    }
  }
}

__global__ __launch_bounds__(512, 2) void attn_kernel(
    const short* __restrict__ qb, const short* __restrict__ kb,
    const short* __restrict__ vtb, short* __restrict__ partial) {
  __shared__ __align__(16) short lds[2][64 * 512];  // 128 KB
  const int tid = threadIdx.x;
  const int l = tid & 63, w = tid >> 6;
  const int g = l >> 4, lr = l & 15;
  // XCD-aware decode: blocks sharing an s-chunk pair live on one XCD so the
  // per-XCD L2 working set is qb(2MB) + its K/V slices(0.5MB) < 4MB.
  const int lin = blockIdx.x;       // 0..255
  const int xcd = lin & 7;
  const int j = lin >> 3;           // 0..31
  const int sc = xcd * 2 + (j & 1); // 0..15
  const int tblk = j >> 1;          // 0..15
  const int tb16 = tblk * 8 + w;    // 0..127

  f32x4 oacc[8][4];
#pragma unroll
  for (int b = 0; b < 8; b++)
#pragma unroll
    for (int df = 0; df < 4; df++) oacc[b][df] = (f32x4){0.f, 0.f, 0.f, 0.f};

  // prologue: stage step 0
  stage_step(kb, vtb, &lds[0][0], w, l, sc * 4 + 0);
  __syncthreads();

  for (int it = 0; it < 4; it++) {
    const int cur = it & 1;
    short* ldsc = &lds[cur][0];

    // ---- issue async staging of next step FIRST: overlaps all of compute.
    // Safe: the __syncthreads ending iter it-1 guarantees every wave finished
    // reading lds[cur^1].
    if (it + 1 < 4) stage_step(kb, vtb, &lds[cur ^ 1][0], w, l, sc * 4 + it + 1);

    // ---- QK^T: S[b][sf] = scaled-scores^T (s = sblk*32+sf*16+g*4+r, t = tb16*16+lr)
    f32x4 S[8][2];
#pragma unroll
    for (int b = 0; b < 8; b++) {
      const short* qbase = qb + (size_t)((b * 128 + tb16) * 2) * 512;
      short8 q0 = *(const short8*)(qbase + l * 8);
      short8 q1 = *(const short8*)(qbase + 512 + l * 8);
#pragma unroll
      for (int sf = 0; sf < 2; sf++) {
        short8 kf0 = *(const short8*)&ldsc[(b * 4 + sf * 2 + 0) * 512 + l * 8];
        short8 kf1 = *(const short8*)&ldsc[(b * 4 + sf * 2 + 1) * 512 + l * 8];
        f32x4 s = (f32x4){0.f, 0.f, 0.f, 0.f};
        s = MFMA16(kf0, q0, s);
        s = MFMA16(kf1, q1, s);
        S[b][sf] = s;
      }
    }

    // ---- softmax over batch (elementwise; q pre-scaled by log2 e -> 2^x)
#pragma unroll
    for (int sf = 0; sf < 2; sf++)
#pragma unroll
      for (int r = 0; r < 4; r++) {
        float den = 0.f;
#pragma unroll
        for (int b = 0; b < 8; b++) {
          float e = __builtin_amdgcn_exp2f(S[b][sf][r]);
          S[b][sf][r] = e;
          den += e;
        }
        float inv = __builtin_amdgcn_rcpf(den);
#pragma unroll
        for (int b = 0; b < 8; b++) S[b][sf][r] *= inv;
      }

    // ---- pack P to bf16 and PV
#pragma unroll
    for (int b = 0; b < 8; b++) {
      uint4_t pw;
      pw[0] = cvt_pk_bf16(S[b][0][0], S[b][0][1]);
      pw[1] = cvt_pk_bf16(S[b][0][2], S[b][0][3]);
      pw[2] = cvt_pk_bf16(S[b][1][0], S[b][1][1]);
      pw[3] = cvt_pk_bf16(S[b][1][2], S[b][1][3]);
      short8 pb = __builtin_bit_cast(short8, pw);
#pragma unroll
      for (int df = 0; df < 4; df++) {
        short8 vf = *(const short8*)&ldsc[(32 + b * 4 + df) * 512 + l * 8];
        oacc[b][df] = MFMA16(vf, pb, oacc[b][df]);
      }
    }
    __syncthreads();  // vmcnt(0) here is ~free: QK's Q-load waits already
                      // retired the stage loads (vmcnt retires in order).
  }

  // ---- store bf16 partial [sc][b][t][d] (streamed; bypass L2)
  const int t = tblk * 128 + w * 16 + lr;
#pragma unroll
  for (int b = 0; b < 8; b++)
#pragma unroll
    for (int df = 0; df < 4; df++) {
      uint2_t pk;
      pk[0] = cvt_pk_bf16(oacc[b][df][0], oacc[b][df][1]);
      pk[1] = cvt_pk_bf16(oacc[b][df][2], oacc[b][df][3]);
      __builtin_nontemporal_store(
          pk, (uint2_t*)&partial[(size_t)(((sc * 8 + b) * 2048 + t)) * 64 + df * 16 + g * 4]);
    }
}

// ---------------- Kernel 3: reduce bf16 partials -> f32 out ----------------
__global__ __launch_bounds__(256) void reduce_kernel(const short* __restrict__ partial,
                                                     float* __restrict__ out) {
  int i = blockIdx.x * 256 + threadIdx.x;  // 0..131071, 8-element groups
  const short8* p = (const short8*)partial;
  float acc[8];
#pragma unroll
  for (int j = 0; j < 8; j++) acc[j] = 0.f;
  for (int sc = 0; sc < 16; sc++) {
    short8 v = __builtin_nontemporal_load(&p[(size_t)sc * 131072 + i]);
#pragma unroll
    for (int j = 0; j < 8; j++)
      acc[j] += __builtin_bit_cast(float, ((unsigned)(unsigned short)v[j]) << 16);
  }
  float4_t o0 = (float4_t){acc[0], acc[1], acc[2], acc[3]};
  float4_t o1 = (float4_t){acc[4], acc[5], acc[6], acc[7]};
  __builtin_nontemporal_store(o0, (float4_t*)&out[(size_t)i * 8]);
  __builtin_nontemporal_store(o1, (float4_t*)&out[(size_t)i * 8 + 4]);
}

extern "C" void kernel_launch(void* const* d_in, const int* in_sizes, int n_in,
                              void* d_out, int out_size, void* d_ws, size_t ws_size,
                              hipStream_t stream) {
  const float* x = (const float*)d_in[0];
  const float* Wq = (const float*)d_in[1];
  const float* Wk = (const float*)d_in[2];
  const float* Wv = (const float*)d_in[3];
  float* out = (float*)d_out;

  char* ws = (char*)d_ws;
  short* qb = (short*)ws;                    // 2MB
  short* kb = qb + 16384 * 64;               // 2MB
  short* vtb = kb + 16384 * 64;              // 2MB
  short* partial = vtb + 16384 * 64;         // 32MB bf16 [16][8][2048][64]

  proj_kernel<<<256, 512, 0, stream>>>(x, Wq, Wk, Wv, qb, kb, vtb);
  attn_kernel<<<256, 512, 0, stream>>>(qb, kb, vtb, partial);
  reduce_kernel<<<512, 256, 0, stream>>>(partial, out);
}

// Round 5
// 105.829 us; speedup vs baseline: 1.0122x; 1.0122x over previous
//
#include <hip/hip_runtime.h>
#include <hip/hip_bf16.h>

// B=8, T=2048, E=1024, H=64
// Round 5:
//  - attn: Q fully hoisted to registers (no per-step global loads) -> staging
//    issued at top-of-step overlaps whole compute with no vmcnt coupling.
//    softmax/PV split per 16-s half (S=32 regs); PV via mfma 16x16x16 so
//    qf(64)+oacc(128)+S(32)+temps fits 256 VGPR at 2 waves/SIMD.
//  - partial stores fragment-major: 8B/lane wave-contiguous NT runs (fixes
//    the 3.5x write amplification seen in WRITE_SIZE=113MB vs 32 logical).
//  - W pre-transposed+converted to bf16 by wprep kernel; proj stages W via
//    vector loads and converts x via v_cvt_pk_bf16_f32.
// Workspace: qb 2MB | kb 2MB | vtb 2MB | partial 33.5MB | Wtb 384KB

typedef __attribute__((ext_vector_type(4))) float f32x4;
typedef __attribute__((ext_vector_type(4))) float float4_t;
typedef __attribute__((ext_vector_type(8))) short short8;
typedef __attribute__((ext_vector_type(4))) short short4_t;
typedef __attribute__((ext_vector_type(4))) unsigned uint4_t;
typedef __attribute__((ext_vector_type(2))) unsigned uint2_t;

#define MFMA32(a, b, c) __builtin_amdgcn_mfma_f32_16x16x32_bf16(a, b, c, 0, 0, 0)
#define MFMA16(a, b, c) __builtin_amdgcn_mfma_f32_16x16x16bf16_1k(a, b, c, 0, 0, 0)

__device__ __forceinline__ short f2bf(float f) {
  unsigned u = __builtin_bit_cast(unsigned, f);
  unsigned r = (u + 0x7FFFu + ((u >> 16) & 1u)) >> 16;  // RNE
  return (short)r;
}

__device__ __forceinline__ unsigned cvt_pk_bf16(float lo, float hi) {
  unsigned r;
  asm volatile("v_cvt_pk_bf16_f32 %0, %1, %2" : "=v"(r) : "v"(lo), "v"(hi));
  return r;  // low16=bf16(lo), high16=bf16(hi)
}

__device__ __forceinline__ void gload16(const short* g, short* l) {
  __builtin_amdgcn_global_load_lds(
      (const __attribute__((address_space(1))) unsigned*)g,
      (__attribute__((address_space(3))) unsigned*)l, 16, 0, 0);
}

// ---------------- Kernel 0: W transpose+convert ----------------
// Wtb[wi][n][k] bf16, n in [0,64), k in [0,1024)
__global__ __launch_bounds__(256) void wprep_kernel(
    const float* __restrict__ Wq, const float* __restrict__ Wk,
    const float* __restrict__ Wv, short* __restrict__ Wtb) {
  int lin = blockIdx.x * 256 + threadIdx.x;  // 24576 threads
  int n = lin & 63;
  int k8 = (lin >> 6) & 127;
  int wi = lin >> 13;
  const float* W = (wi == 0) ? Wq : (wi == 1) ? Wk : Wv;
  short* dst = Wtb + wi * 65536 + n * 1024 + k8 * 8;
#pragma unroll
  for (int i = 0; i < 8; i++) dst[i] = f2bf(W[(k8 * 8 + i) * 64 + n]);
}

// ---------------- Kernel 1: merged QKV projection ----------------
//  qb: (((b*128 + t>>4)*2 + d>>5)*64 + lane)*8 + (d&7),  lane=(((d>>3)&3)<<4)|(t&15)
//  kb: ((((b*64 + s>>5)*2 + (s>>4)&1)*2 + d>>5)*64 + lane)*8 + (d&7)
//  vtb: ((b*4 + d>>4)*64 + s>>5)*512 + ((((s>>2)&3)*16 + (d&15))*8) + ((s>>4)&1)*4 + (s&3)
__global__ __launch_bounds__(512) void proj_kernel(
    const float* __restrict__ x, const short* __restrict__ Wtb,
    short* __restrict__ qb, short* __restrict__ kb, short* __restrict__ vtb) {
  __shared__ __align__(16) short lds_A[64 * 72];
  __shared__ __align__(16) short lds_W[3][64 * 72];
  const int tid = threadIdx.x;
  const int m0 = blockIdx.x * 64;
  const int l = tid & 63, w = tid >> 6;
  const int g = l >> 4, lr = l & 15;
  const int wr = w & 3, wc = w >> 2;

  f32x4 acc[6];
#pragma unroll
  for (int i = 0; i < 6; i++) acc[i] = (f32x4){0.f, 0.f, 0.f, 0.f};

  for (int k0 = 0; k0 < 1024; k0 += 64) {
    __syncthreads();
    {  // stage x tile (64x64, f32 -> bf16 via cvt_pk)
      int row = tid >> 3;
      int k8 = (tid & 7) * 8;
      const float* src = x + (m0 + row) * 1024 + k0 + k8;
      float4_t f0 = __builtin_nontemporal_load((const float4_t*)src);
      float4_t f1 = __builtin_nontemporal_load((const float4_t*)(src + 4));
      uint4_t u;
      u[0] = cvt_pk_bf16(f0[0], f0[1]);
      u[1] = cvt_pk_bf16(f0[2], f0[3]);
      u[2] = cvt_pk_bf16(f1[0], f1[1]);
      u[3] = cvt_pk_bf16(f1[2], f1[3]);
      *(short8*)&lds_A[row * 72 + k8] = __builtin_bit_cast(short8, u);
    }
    {  // stage W tiles (already transposed bf16)
      int n = tid & 63;
      int kk0 = (tid >> 6) * 8;
#pragma unroll
      for (int wi = 0; wi < 3; wi++)
        *(short8*)&lds_W[wi][n * 72 + kk0] =
            *(const short8*)&Wtb[wi * 65536 + n * 1024 + k0 + kk0];
    }
    __syncthreads();
#pragma unroll
    for (int ks = 0; ks < 2; ks++) {
      short8 a = *(const short8*)&lds_A[(wr * 16 + lr) * 72 + ks * 32 + g * 8];
#pragma unroll
      for (int nf = 0; nf < 6; nf++) {
        int colg0 = wc * 96 + nf * 16;
        short8 bfrag = *(const short8*)&lds_W[colg0 >> 6][((colg0 & 63) + lr) * 72 + ks * 32 + g * 8];
        acc[nf] = MFMA32(a, bfrag, acc[nf]);
      }
    }
  }
#pragma unroll
  for (int nf = 0; nf < 6; nf++) {
    int colg0 = wc * 96 + nf * 16;
    int wi = colg0 >> 6;
    int d = (colg0 & 63) + lr;
    // fold 1/sqrt(H)*log2(e) into q so attn softmax uses 2^x directly
    float scale = (wi == 0) ? 0.18033688f : 1.0f;
#pragma unroll
    for (int r = 0; r < 4; r++) {
      int row = m0 + wr * 16 + g * 4 + r;
      int b = row >> 11, t = row & 2047;  // t is also V's token index s
      short bv = f2bf(acc[nf][r] * scale);
      if (wi == 0) {
        int idx = (((b * 128 + (t >> 4)) * 2 + (d >> 5)) * 64 +
                   ((((d >> 3) & 3) << 4) | (t & 15))) * 8 + (d & 7);
        qb[idx] = bv;
      } else if (wi == 1) {
        int idx = ((((b * 64 + (t >> 5)) * 2 + ((t >> 4) & 1)) * 2 + (d >> 5)) * 64 +
                   ((((d >> 3) & 3) << 4) | (t & 15))) * 8 + (d & 7);
        kb[idx] = bv;
      } else {
        int idx = ((b * 4 + (d >> 4)) * 64 + (t >> 5)) * 512 +
                  ((((t >> 2) & 3) * 16 + (d & 15)) * 8) + (((t >> 4) & 1) << 2) + (t & 3);
        vtb[idx] = bv;
      }
    }
  }
}

// ---------------- Kernel 2: pipelined fused attention ----------------
// LDS frags (512 shorts = 1KB): f in [0,32) K (f = b*4 + sf*2 + ks);
// f in [32,64) V (f = 32 + b*4 + df; lane's 16B = [sf0: 4 shorts][sf1: 4 shorts]).
__device__ __forceinline__ void stage_step(const short* __restrict__ kb,
                                           const short* __restrict__ vtb,
                                           short* lds_buf, int w, int l, int sblk) {
  if (w < 4) {
#pragma unroll
    for (int i = 0; i < 8; i++) {
      int f = w * 8 + i;  // K frag
      const short* src = kb + (size_t)((f >> 2) * 256 + sblk * 4 + (f & 3)) * 512 + l * 8;
      gload16(src, lds_buf + f * 512);
    }
  } else {
#pragma unroll
    for (int i = 0; i < 8; i++) {
      int fv = (w - 4) * 8 + i;  // V frag
      const short* src = vtb + (size_t)(fv * 64 + sblk) * 512 + l * 8;
      gload16(src, lds_buf + (32 + fv) * 512);
    }
  }
}

__global__ __launch_bounds__(512, 2) void attn_kernel(
    const short* __restrict__ qb, const short* __restrict__ kb,
    const short* __restrict__ vtb, short* __restrict__ partial) {
  __shared__ __align__(16) short lds[2][64 * 512];  // 128 KB
  const int tid = threadIdx.x;
  const int l = tid & 63, w = tid >> 6;
  // XCD-aware decode: per-XCD set = qb(2MB) + K/V slices(0.5MB) < 4MB L2.
  const int lin = blockIdx.x;  // 0..255
  const int sc = (lin & 7) * 2 + ((lin >> 3) & 1);
  const int tblk = lin >> 4;
  const int tb16 = tblk * 8 + w;

  // hoist Q: 64 VGPR, loaded once (prologue barrier covers the wait)
  short8 qf[8][2];
#pragma unroll
  for (int b = 0; b < 8; b++)
#pragma unroll
    for (int ks = 0; ks < 2; ks++)
      qf[b][ks] = *(const short8*)&qb[(size_t)((b * 128 + tb16) * 2 + ks) * 512 + l * 8];

  f32x4 oacc[8][4];
#pragma unroll
  for (int b = 0; b < 8; b++)
#pragma unroll
    for (int df = 0; df < 4; df++) oacc[b][df] = (f32x4){0.f, 0.f, 0.f, 0.f};

  stage_step(kb, vtb, &lds[0][0], w, l, sc * 4);
  __syncthreads();

  for (int it = 0; it < 4; it++) {
    const int cur = it & 1;
    short* ldsc = &lds[cur][0];

    // staging of step it+1: no other vmcnt traffic this step -> fully
    // overlapped by compute; drained by the end-of-step barrier.
    if (it + 1 < 4) stage_step(kb, vtb, &lds[cur ^ 1][0], w, l, sc * 4 + it + 1);

#pragma unroll
    for (int sf = 0; sf < 2; sf++) {
      // ---- QK^T for this 16-s half: S[b][r] = scoresT[s=sblk*32+sf*16+g*4+r][t]
      f32x4 S[8];
#pragma unroll
      for (int b = 0; b < 8; b++) {
        short8 kf0 = *(const short8*)&ldsc[(b * 4 + sf * 2 + 0) * 512 + l * 8];
        short8 kf1 = *(const short8*)&ldsc[(b * 4 + sf * 2 + 1) * 512 + l * 8];
        f32x4 s = (f32x4){0.f, 0.f, 0.f, 0.f};
        s = MFMA32(kf0, qf[b][0], s);
        s = MFMA32(kf1, qf[b][1], s);
        S[b] = s;
      }
      // ---- softmax over batch (elementwise across the 8 register sets)
#pragma unroll
      for (int r = 0; r < 4; r++) {
        float den = 0.f;
#pragma unroll
        for (int b = 0; b < 8; b++) {
          float e = __builtin_amdgcn_exp2f(S[b][r]);
          S[b] [r] = e;
          den += e;
        }
        float inv = __builtin_amdgcn_rcpf(den);
#pragma unroll
        for (int b = 0; b < 8; b++) S[b][r] *= inv;
      }
      // ---- pack P half and PV via 16x16x16 (k=16)
#pragma unroll
      for (int b = 0; b < 8; b++) {
        uint2_t pw;
        pw[0] = cvt_pk_bf16(S[b][0], S[b][1]);
        pw[1] = cvt_pk_bf16(S[b][2], S[b][3]);
        short4_t pb = __builtin_bit_cast(short4_t, pw);
#pragma unroll
        for (int df = 0; df < 4; df++) {
          short4_t vf = *(const short4_t*)&ldsc[(32 + b * 4 + df) * 512 + l * 8 + sf * 4];
          oacc[b][df] = MFMA16(vf, pb, oacc[b][df]);
        }
      }
    }
    __syncthreads();
  }

  // ---- store partial fragment-major: uint2 per lane, wave-contiguous 512B runs
  uint2_t* pout = (uint2_t*)partial;
#pragma unroll
  for (int b = 0; b < 8; b++)
#pragma unroll
    for (int df = 0; df < 4; df++) {
      uint2_t pk;
      pk[0] = cvt_pk_bf16(oacc[b][df][0], oacc[b][df][1]);
      pk[1] = cvt_pk_bf16(oacc[b][df][2], oacc[b][df][3]);
      __builtin_nontemporal_store(
          pk, &pout[(size_t)(((sc * 8 + b) * 128 + tb16) * 4 + df) * 64 + l]);
    }
}

// ---------------- Kernel 3: reduce bf16 partials -> f32 out ----------------
__global__ __launch_bounds__(256) void reduce_kernel(const short* __restrict__ partial,
                                                     float* __restrict__ out) {
  int i = blockIdx.x * 256 + threadIdx.x;  // 0..262143: (b,tb16,df,l)
  const uint2_t* p = (const uint2_t*)partial;
  float4_t a = (float4_t){0.f, 0.f, 0.f, 0.f};
  for (int sc = 0; sc < 16; sc++) {
    uint2_t v = __builtin_nontemporal_load(&p[(size_t)sc * 262144 + i]);
    a[0] += __builtin_bit_cast(float, v[0] << 16);
    a[1] += __builtin_bit_cast(float, v[0] & 0xFFFF0000u);
    a[2] += __builtin_bit_cast(float, v[1] << 16);
    a[3] += __builtin_bit_cast(float, v[1] & 0xFFFF0000u);
  }
  int b = i >> 15;
  int r1 = i & 32767;
  int tb16 = r1 >> 8;
  int r2 = r1 & 255;
  int df = r2 >> 6;
  int ll = r2 & 63;
  int gg = ll >> 4, lrr = ll & 15;
  *(float4_t*)&out[(size_t)(b * 2048 + tb16 * 16 + lrr) * 64 + df * 16 + gg * 4] = a;
}

extern "C" void kernel_launch(void* const* d_in, const int* in_sizes, int n_in,
                              void* d_out, int out_size, void* d_ws, size_t ws_size,
                              hipStream_t stream) {
  const float* x = (const float*)d_in[0];
  const float* Wq = (const float*)d_in[1];
  const float* Wk = (const float*)d_in[2];
  const float* Wv = (const float*)d_in[3];
  float* out = (float*)d_out;

  char* ws = (char*)d_ws;
  short* qb = (short*)ws;                    // 2MB
  short* kb = qb + 16384 * 64;               // 2MB
  short* vtb = kb + 16384 * 64;              // 2MB
  short* partial = vtb + 16384 * 64;         // 33.5MB bf16 fragment-major
  short* Wtb = partial + 16ull * 262144 * 4; // 384KB

  wprep_kernel<<<96, 256, 0, stream>>>(Wq, Wk, Wv, Wtb);
  proj_kernel<<<256, 512, 0, stream>>>(x, Wtb, qb, kb, vtb);
  attn_kernel<<<256, 512, 0, stream>>>(qb, kb, vtb, partial);
  reduce_kernel<<<1024, 256, 0, stream>>>(partial, out);
}

// Round 6
// 92.583 us; speedup vs baseline: 1.1570x; 1.1431x over previous
//
#include <hip/hip_runtime.h>
#include <hip/hip_bf16.h>

// B=8, T=2048, E=1024, H=64
// Round 6: counted-vmcnt pipelined attention (T3+T4 from the 8-phase GEMM
// template): 16-s steps, 4 LDS buffers (128KB), 3-deep prefetch, ONE raw
// s_barrier per step preceded by s_waitcnt vmcnt(8) (never 0 in the loop).
// All LDS reads are stride-16B ds_read_b128 (V frags packed in pairs).
// kb/vtb are one contiguous unit-indexed array -> branchless staging.
// Proj: register double-buffer (next x/W tile loads overlap compute).
//
// Workspace: qb 2MB | kvb 4MB (K units 0..15, V units 16..31) | partial 33.5MB | Wtb 384KB

typedef __attribute__((ext_vector_type(4))) float f32x4;
typedef __attribute__((ext_vector_type(4))) float float4_t;
typedef __attribute__((ext_vector_type(8))) short short8;
typedef __attribute__((ext_vector_type(4))) short short4_t;
typedef __attribute__((ext_vector_type(4))) unsigned uint4_t;
typedef __attribute__((ext_vector_type(2))) unsigned uint2_t;

#define MFMA32(a, b, c) __builtin_amdgcn_mfma_f32_16x16x32_bf16(a, b, c, 0, 0, 0)
#define MFMA16(a, b, c) __builtin_amdgcn_mfma_f32_16x16x16bf16_1k(a, b, c, 0, 0, 0)

__device__ __forceinline__ short f2bf(float f) {
  unsigned u = __builtin_bit_cast(unsigned, f);
  unsigned r = (u + 0x7FFFu + ((u >> 16) & 1u)) >> 16;  // RNE
  return (short)r;
}

__device__ __forceinline__ unsigned cvt_pk_bf16(float lo, float hi) {
  unsigned r;
  asm volatile("v_cvt_pk_bf16_f32 %0, %1, %2" : "=v"(r) : "v"(lo), "v"(hi));
  return r;
}

__device__ __forceinline__ void gload16(const short* g, short* l) {
  __builtin_amdgcn_global_load_lds(
      (const __attribute__((address_space(1))) unsigned*)g,
      (__attribute__((address_space(3))) unsigned*)l, 16, 0, 0);
}

// ---------------- Kernel 0: W transpose+convert ----------------
__global__ __launch_bounds__(256) void wprep_kernel(
    const float* __restrict__ Wq, const float* __restrict__ Wk,
    const float* __restrict__ Wv, short* __restrict__ Wtb) {
  int lin = blockIdx.x * 256 + threadIdx.x;  // 24576 threads
  int n = lin & 63;
  int k8 = (lin >> 6) & 127;
  int wi = lin >> 13;
  const float* W = (wi == 0) ? Wq : (wi == 1) ? Wk : Wv;
  short* dst = Wtb + wi * 65536 + n * 1024 + k8 * 8;
#pragma unroll
  for (int i = 0; i < 8; i++) dst[i] = f2bf(W[(k8 * 8 + i) * 64 + n]);
}

// ---------------- Kernel 1: merged QKV projection ----------------
// Output layouts (s16 = token>>4, one 1KB "unit" = 64 lanes x 16B):
//  qb  unit (b,tb16,ks): qb + ((b*128+tb16)*2+ks)*512 + l*8 + j
//       (l = ((d>>3)&3)<<4 | (t&15), j = d&7, d = 32ks + 8*(l>>4) + j)
//  kvb K unit u=b*2+ks   (u<16) : kvb + (u*128+s16)*512 + l*8 + j   (same l/j map, s)
//  kvb V unit u=16+b*2+dp (dp=d>>5): kvb + (u*128+s16)*512 + l*8 + hB*4 + (s&3)
//       (l = ((s>>2)&3)<<4 | (d&15), hB = (d>>4)&1)
__global__ __launch_bounds__(512) void proj_kernel(
    const float* __restrict__ x, const short* __restrict__ Wtb,
    short* __restrict__ qb, short* __restrict__ kvb) {
  __shared__ __align__(16) short lds_A[64 * 72];
  __shared__ __align__(16) short lds_W[3][64 * 72];
  const int tid = threadIdx.x;
  const int m0 = blockIdx.x * 64;
  const int l = tid & 63, w = tid >> 6;
  const int g = l >> 4, lr = l & 15;
  const int wr = w & 3, wc = w >> 2;
  const int xrow = tid >> 3, xk8 = (tid & 7) * 8;
  const int wn = tid & 63, wk0 = (tid >> 6) * 8;

  f32x4 acc[6];
#pragma unroll
  for (int i = 0; i < 6; i++) acc[i] = (f32x4){0.f, 0.f, 0.f, 0.f};

  // preload tile 0 into registers
  const float* xsrc = x + (m0 + xrow) * 1024 + xk8;
  float4_t xf0 = __builtin_nontemporal_load((const float4_t*)xsrc);
  float4_t xf1 = __builtin_nontemporal_load((const float4_t*)(xsrc + 4));
  short8 wv0 = *(const short8*)&Wtb[0 * 65536 + wn * 1024 + wk0];
  short8 wv1 = *(const short8*)&Wtb[1 * 65536 + wn * 1024 + wk0];
  short8 wv2 = *(const short8*)&Wtb[2 * 65536 + wn * 1024 + wk0];

  for (int k0 = 0; k0 < 1024; k0 += 64) {
    __syncthreads();  // previous compute done -> LDS reusable
    {
      uint4_t u;
      u[0] = cvt_pk_bf16(xf0[0], xf0[1]);
      u[1] = cvt_pk_bf16(xf0[2], xf0[3]);
      u[2] = cvt_pk_bf16(xf1[0], xf1[1]);
      u[3] = cvt_pk_bf16(xf1[2], xf1[3]);
      *(short8*)&lds_A[xrow * 72 + xk8] = __builtin_bit_cast(short8, u);
      *(short8*)&lds_W[0][wn * 72 + wk0] = wv0;
      *(short8*)&lds_W[1][wn * 72 + wk0] = wv1;
      *(short8*)&lds_W[2][wn * 72 + wk0] = wv2;
    }
    __syncthreads();
    // prefetch next tile (overlaps compute below)
    if (k0 + 64 < 1024) {
      const float* xs = x + (m0 + xrow) * 1024 + k0 + 64 + xk8;
      xf0 = __builtin_nontemporal_load((const float4_t*)xs);
      xf1 = __builtin_nontemporal_load((const float4_t*)(xs + 4));
      wv0 = *(const short8*)&Wtb[0 * 65536 + wn * 1024 + k0 + 64 + wk0];
      wv1 = *(const short8*)&Wtb[1 * 65536 + wn * 1024 + k0 + 64 + wk0];
      wv2 = *(const short8*)&Wtb[2 * 65536 + wn * 1024 + k0 + 64 + wk0];
    }
#pragma unroll
    for (int ks = 0; ks < 2; ks++) {
      short8 a = *(const short8*)&lds_A[(wr * 16 + lr) * 72 + ks * 32 + g * 8];
#pragma unroll
      for (int nf = 0; nf < 6; nf++) {
        int colg0 = wc * 96 + nf * 16;
        short8 bfrag = *(const short8*)&lds_W[colg0 >> 6][((colg0 & 63) + lr) * 72 + ks * 32 + g * 8];
        acc[nf] = MFMA32(a, bfrag, acc[nf]);
      }
    }
  }
#pragma unroll
  for (int nf = 0; nf < 6; nf++) {
    int colg0 = wc * 96 + nf * 16;
    int wi = colg0 >> 6;
    int d = (colg0 & 63) + lr;
    // fold 1/sqrt(H)*log2(e) into q so attn softmax uses 2^x directly
    float scale = (wi == 0) ? 0.18033688f : 1.0f;
#pragma unroll
    for (int r = 0; r < 4; r++) {
      int row = m0 + wr * 16 + g * 4 + r;
      int b = row >> 11, t = row & 2047;
      short bv = f2bf(acc[nf][r] * scale);
      if (wi == 0) {
        int idx = (((b * 128 + (t >> 4)) * 2 + (d >> 5)) * 64 +
                   ((((d >> 3) & 3) << 4) | (t & 15))) * 8 + (d & 7);
        qb[idx] = bv;
      } else if (wi == 1) {
        int u = (b * 2 + (d >> 5));
        int idx = ((u * 128 + (t >> 4)) << 9) +
                  (((((d >> 3) & 3) << 4) | (t & 15)) << 3) + (d & 7);
        kvb[idx] = bv;
      } else {
        int u = 16 + (b * 2 + (d >> 5));
        int idx = ((u * 128 + (t >> 4)) << 9) +
                  (((((t >> 2) & 3) << 4) | (d & 15)) << 3) + (((d >> 4) & 1) << 2) + (t & 3);
        kvb[idx] = bv;
      }
    }
  }
}

// ---------------- Kernel 2: counted-vmcnt pipelined attention ----------------
// Buffer = 32KB = 32 units x 1KB. Units: u<16 K (u=b*2+ks); u>=16 V pair
// (u=16+b*2+dp; lane 16B = [fragA df=2dp 8B | fragB df=2dp+1 8B]).
__device__ __forceinline__ void stage_step(const short* __restrict__ kvb,
                                           short* lds_buf, int w, int l, int s16) {
#pragma unroll
  for (int i = 0; i < 4; i++) {
    int u = w * 4 + i;
    const short* src = kvb + (((size_t)u * 128 + s16) << 9) + l * 8;
    gload16(src, lds_buf + u * 512);
  }
}

__device__ __forceinline__ void consume_step(const short* __restrict__ ldsc,
                                             const short8 (&qf)[8][2],
                                             f32x4 (&oacc)[8][4], int l) {
  f32x4 S[8];
#pragma unroll
  for (int b = 0; b < 8; b++) {
    short8 kf0 = *(const short8*)&ldsc[(b * 2 + 0) * 512 + l * 8];
    short8 kf1 = *(const short8*)&ldsc[(b * 2 + 1) * 512 + l * 8];
    f32x4 s = (f32x4){0.f, 0.f, 0.f, 0.f};
    s = MFMA32(kf0, qf[b][0], s);
    s = MFMA32(kf1, qf[b][1], s);
    S[b] = s;
  }
  // softmax over batch: elementwise across the 8 register sets (q pre-scaled by log2e)
#pragma unroll
  for (int r = 0; r < 4; r++) {
    float den = 0.f;
#pragma unroll
    for (int b = 0; b < 8; b++) {
      float e = __builtin_amdgcn_exp2f(S[b][r]);
      S[b][r] = e;
      den += e;
    }
    float inv = __builtin_amdgcn_rcpf(den);
#pragma unroll
    for (int b = 0; b < 8; b++) S[b][r] *= inv;
  }
#pragma unroll
  for (int b = 0; b < 8; b++) {
    uint2_t pw;
    pw[0] = cvt_pk_bf16(S[b][0], S[b][1]);
    pw[1] = cvt_pk_bf16(S[b][2], S[b][3]);
    short4_t pb = __builtin_bit_cast(short4_t, pw);
#pragma unroll
    for (int dp = 0; dp < 2; dp++) {
      short8 vf = *(const short8*)&ldsc[(16 + b * 2 + dp) * 512 + l * 8];
      short4_t va = __builtin_shufflevector(vf, vf, 0, 1, 2, 3);
      short4_t vb = __builtin_shufflevector(vf, vf, 4, 5, 6, 7);
      oacc[b][dp * 2 + 0] = MFMA16(va, pb, oacc[b][dp * 2 + 0]);
      oacc[b][dp * 2 + 1] = MFMA16(vb, pb, oacc[b][dp * 2 + 1]);
    }
  }
}

template <int IT>
__device__ __forceinline__ void attn_step(const short* __restrict__ kvb, short* lds,
                                          const short8 (&qf)[8][2], f32x4 (&oacc)[8][4],
                                          int w, int l, int sc) {
  // buffer IT's 4 loads are always followed by >=8 younger loads (bufs IT+1,
  // IT+2) while they exist -> vmcnt(8) retires buf IT; tail steps shrink.
  constexpr int NW = (IT <= 5) ? 8 : (7 - IT) * 4;
  asm volatile("s_waitcnt vmcnt(%0)" ::"n"(NW) : "memory");
  __builtin_amdgcn_s_barrier();  // all waves: buf IT complete, prev reads done
  __builtin_amdgcn_sched_barrier(0);
  if constexpr (IT + 3 < 8)
    stage_step(kvb, lds + ((IT + 3) & 3) * 16384, w, l, sc * 8 + IT + 3);
  __builtin_amdgcn_sched_barrier(0);
  consume_step(lds + (IT & 3) * 16384, qf, oacc, l);
}

__global__ __launch_bounds__(512, 2) void attn_kernel(
    const short* __restrict__ qb, const short* __restrict__ kvb,
    short* __restrict__ partial) {
  __shared__ __align__(16) short lds[4 * 16384];  // 128 KB: 4 x 32KB buffers
  const int tid = threadIdx.x;
  const int l = tid & 63, w = tid >> 6;
  // XCD-aware decode: blocks sharing an s-chunk pair on one XCD
  const int lin = blockIdx.x;  // 0..255
  const int sc = (lin & 7) * 2 + ((lin >> 3) & 1);  // 0..15, owns 128 s
  const int tblk = lin >> 4;                        // 0..15
  const int tb16 = tblk * 8 + w;                    // 0..127

  // Q hoisted: 16 x b128 (compiler inserts the wait before first use)
  short8 qf[8][2];
#pragma unroll
  for (int b = 0; b < 8; b++)
#pragma unroll
    for (int ks = 0; ks < 2; ks++)
      qf[b][ks] = *(const short8*)&qb[(size_t)((b * 128 + tb16) * 2 + ks) * 512 + l * 8];

  f32x4 oacc[8][4];
#pragma unroll
  for (int b = 0; b < 8; b++)
#pragma unroll
    for (int df = 0; df < 4; df++) oacc[b][df] = (f32x4){0.f, 0.f, 0.f, 0.f};

  // prologue: stage buffers 0..2 (12 loads in flight)
  stage_step(kvb, lds + 0 * 16384, w, l, sc * 8 + 0);
  stage_step(kvb, lds + 1 * 16384, w, l, sc * 8 + 1);
  stage_step(kvb, lds + 2 * 16384, w, l, sc * 8 + 2);

  attn_step<0>(kvb, lds, qf, oacc, w, l, sc);
  attn_step<1>(kvb, lds, qf, oacc, w, l, sc);
  attn_step<2>(kvb, lds, qf, oacc, w, l, sc);
  attn_step<3>(kvb, lds, qf, oacc, w, l, sc);
  attn_step<4>(kvb, lds, qf, oacc, w, l, sc);
  attn_step<5>(kvb, lds, qf, oacc, w, l, sc);
  attn_step<6>(kvb, lds, qf, oacc, w, l, sc);
  attn_step<7>(kvb, lds, qf, oacc, w, l, sc);

  // store bf16 partial fragment-major: uint2/lane, wave-contiguous 512B runs
  const int g = l >> 4;
  uint2_t* pout = (uint2_t*)partial;
#pragma unroll
  for (int b = 0; b < 8; b++)
#pragma unroll
    for (int df = 0; df < 4; df++) {
      uint2_t pk;
      pk[0] = cvt_pk_bf16(oacc[b][df][0], oacc[b][df][1]);
      pk[1] = cvt_pk_bf16(oacc[b][df][2], oacc[b][df][3]);
      __builtin_nontemporal_store(
          pk, &pout[(size_t)(((sc * 8 + b) * 128 + tb16) * 4 + df) * 64 + l]);
    }
  (void)g;
}

// ---------------- Kernel 3: reduce bf16 partials -> f32 out ----------------
__global__ __launch_bounds__(256) void reduce_kernel(const short* __restrict__ partial,
                                                     float* __restrict__ out) {
  int i = blockIdx.x * 256 + threadIdx.x;  // 0..262143: (b,tb16,df,l)
  const uint2_t* p = (const uint2_t*)partial;
  float4_t a = (float4_t){0.f, 0.f, 0.f, 0.f};
  for (int sc = 0; sc < 16; sc++) {
    uint2_t v = __builtin_nontemporal_load(&p[(size_t)sc * 262144 + i]);
    a[0] += __builtin_bit_cast(float, v[0] << 16);
    a[1] += __builtin_bit_cast(float, v[0] & 0xFFFF0000u);
    a[2] += __builtin_bit_cast(float, v[1] << 16);
    a[3] += __builtin_bit_cast(float, v[1] & 0xFFFF0000u);
  }
  int b = i >> 15;
  int r1 = i & 32767;
  int tb16 = r1 >> 8;
  int r2 = r1 & 255;
  int df = r2 >> 6;
  int ll = r2 & 63;
  int gg = ll >> 4, lrr = ll & 15;
  *(float4_t*)&out[(size_t)(b * 2048 + tb16 * 16 + lrr) * 64 + df * 16 + gg * 4] = a;
}

extern "C" void kernel_launch(void* const* d_in, const int* in_sizes, int n_in,
                              void* d_out, int out_size, void* d_ws, size_t ws_size,
                              hipStream_t stream) {
  const float* x = (const float*)d_in[0];
  const float* Wq = (const float*)d_in[1];
  const float* Wk = (const float*)d_in[2];
  const float* Wv = (const float*)d_in[3];
  float* out = (float*)d_out;

  char* ws = (char*)d_ws;
  short* qb = (short*)ws;                     // 2MB
  short* kvb = qb + 16384 * 64;               // 4MB (K units 0..15, V units 16..31)
  short* partial = kvb + 2 * 16384 * 64;      // 33.5MB bf16 fragment-major
  short* Wtb = partial + 16ull * 262144 * 4;  // 384KB

  wprep_kernel<<<96, 256, 0, stream>>>(Wq, Wk, Wv, Wtb);
  proj_kernel<<<256, 512, 0, stream>>>(x, Wtb, qb, kvb);
  attn_kernel<<<256, 512, 0, stream>>>(qb, kvb, partial);
  reduce_kernel<<<1024, 256, 0, stream>>>(partial, out);
}

// Round 7
// 90.775 us; speedup vs baseline: 1.1800x; 1.0199x over previous
//
#include <hip/hip_runtime.h>
#include <hip/hip_bf16.h>

// B=8, T=2048, E=1024, H=64
// Round 7: 32-s steps with k=32 MFMA for PV (drop the suspect 16x16x16_1k
// legacy opcode), d-split waves (oacc 64 AGPR, V reads halved, QK dup'd x2
// on an 8.5%-busy MFMA pipe), 2x64KB LDS ring with stage-after-barrier
// (__syncthreads vmcnt(0) drains only step-old loads -> free), setprio
// around MFMA clusters. Q hoisted; merged kvb; XCD-aware decode kept.
//
// kvb layout: window W = s>>5 (64 windows), 64 units of 1KB each:
//   u in [0,32): K  u = b*4 + sf*2 + ks   (sf=(s>>4)&1, ks=d>>5)
//       in-unit: l = ((d>>3)&3)<<4 | (s&15), j = d&7
//   u in [32,64): V u = 32 + b*4 + df     (df=d>>4)
//       in-unit: l = ((s>>2)&3)<<4 | (d&15), j = ((s>>4)&1)*4 + (s&3)
//   (K/Q use k-map d = 32ks+8g+j; P/V use sigma(g,j) = 16(j>>2)+4g+(j&3) --
//    both operands of each MFMA share the same bijection, so HW contraction
//    is exact.)
// Workspace: qb 2MB | kvb 4MB | partial 33.5MB | Wtb 384KB

typedef __attribute__((ext_vector_type(4))) float f32x4;
typedef __attribute__((ext_vector_type(4))) float float4_t;
typedef __attribute__((ext_vector_type(8))) short short8;
typedef __attribute__((ext_vector_type(4))) unsigned uint4_t;
typedef __attribute__((ext_vector_type(2))) unsigned uint2_t;

#define MFMA32(a, b, c) __builtin_amdgcn_mfma_f32_16x16x32_bf16(a, b, c, 0, 0, 0)

__device__ __forceinline__ short f2bf(float f) {
  unsigned u = __builtin_bit_cast(unsigned, f);
  unsigned r = (u + 0x7FFFu + ((u >> 16) & 1u)) >> 16;  // RNE
  return (short)r;
}

__device__ __forceinline__ unsigned cvt_pk_bf16(float lo, float hi) {
  unsigned r;
  asm volatile("v_cvt_pk_bf16_f32 %0, %1, %2" : "=v"(r) : "v"(lo), "v"(hi));
  return r;  // low16=bf16(lo), high16=bf16(hi)
}

__device__ __forceinline__ void gload16(const short* g, short* l) {
  __builtin_amdgcn_global_load_lds(
      (const __attribute__((address_space(1))) unsigned*)g,
      (__attribute__((address_space(3))) unsigned*)l, 16, 0, 0);
}

// ---------------- Kernel 0: W transpose+convert ----------------
__global__ __launch_bounds__(256) void wprep_kernel(
    const float* __restrict__ Wq, const float* __restrict__ Wk,
    const float* __restrict__ Wv, short* __restrict__ Wtb) {
  int lin = blockIdx.x * 256 + threadIdx.x;  // 24576 threads
  int n = lin & 63;
  int k8 = (lin >> 6) & 127;
  int wi = lin >> 13;
  const float* W = (wi == 0) ? Wq : (wi == 1) ? Wk : Wv;
  short* dst = Wtb + wi * 65536 + n * 1024 + k8 * 8;
#pragma unroll
  for (int i = 0; i < 8; i++) dst[i] = f2bf(W[(k8 * 8 + i) * 64 + n]);
}

// ---------------- Kernel 1: merged QKV projection ----------------
__global__ __launch_bounds__(512) void proj_kernel(
    const float* __restrict__ x, const short* __restrict__ Wtb,
    short* __restrict__ qb, short* __restrict__ kvb) {
  __shared__ __align__(16) short lds_A[64 * 72];
  __shared__ __align__(16) short lds_W[3][64 * 72];
  const int tid = threadIdx.x;
  const int m0 = blockIdx.x * 64;
  const int l = tid & 63, w = tid >> 6;
  const int g = l >> 4, lr = l & 15;
  const int wr = w & 3, wc = w >> 2;
  const int xrow = tid >> 3, xk8 = (tid & 7) * 8;
  const int wn = tid & 63, wk0 = (tid >> 6) * 8;

  f32x4 acc[6];
#pragma unroll
  for (int i = 0; i < 6; i++) acc[i] = (f32x4){0.f, 0.f, 0.f, 0.f};

  const float* xsrc = x + (m0 + xrow) * 1024 + xk8;
  float4_t xf0 = __builtin_nontemporal_load((const float4_t*)xsrc);
  float4_t xf1 = __builtin_nontemporal_load((const float4_t*)(xsrc + 4));
  short8 wv0 = *(const short8*)&Wtb[0 * 65536 + wn * 1024 + wk0];
  short8 wv1 = *(const short8*)&Wtb[1 * 65536 + wn * 1024 + wk0];
  short8 wv2 = *(const short8*)&Wtb[2 * 65536 + wn * 1024 + wk0];

  for (int k0 = 0; k0 < 1024; k0 += 64) {
    __syncthreads();
    {
      uint4_t u;
      u[0] = cvt_pk_bf16(xf0[0], xf0[1]);
      u[1] = cvt_pk_bf16(xf0[2], xf0[3]);
      u[2] = cvt_pk_bf16(xf1[0], xf1[1]);
      u[3] = cvt_pk_bf16(xf1[2], xf1[3]);
      *(short8*)&lds_A[xrow * 72 + xk8] = __builtin_bit_cast(short8, u);
      *(short8*)&lds_W[0][wn * 72 + wk0] = wv0;
      *(short8*)&lds_W[1][wn * 72 + wk0] = wv1;
      *(short8*)&lds_W[2][wn * 72 + wk0] = wv2;
    }
    __syncthreads();
    if (k0 + 64 < 1024) {
      const float* xs = x + (m0 + xrow) * 1024 + k0 + 64 + xk8;
      xf0 = __builtin_nontemporal_load((const float4_t*)xs);
      xf1 = __builtin_nontemporal_load((const float4_t*)(xs + 4));
      wv0 = *(const short8*)&Wtb[0 * 65536 + wn * 1024 + k0 + 64 + wk0];
      wv1 = *(const short8*)&Wtb[1 * 65536 + wn * 1024 + k0 + 64 + wk0];
      wv2 = *(const short8*)&Wtb[2 * 65536 + wn * 1024 + k0 + 64 + wk0];
    }
#pragma unroll
    for (int ks = 0; ks < 2; ks++) {
      short8 a = *(const short8*)&lds_A[(wr * 16 + lr) * 72 + ks * 32 + g * 8];
#pragma unroll
      for (int nf = 0; nf < 6; nf++) {
        int colg0 = wc * 96 + nf * 16;
        short8 bfrag = *(const short8*)&lds_W[colg0 >> 6][((colg0 & 63) + lr) * 72 + ks * 32 + g * 8];
        acc[nf] = MFMA32(a, bfrag, acc[nf]);
      }
    }
  }
#pragma unroll
  for (int nf = 0; nf < 6; nf++) {
    int colg0 = wc * 96 + nf * 16;
    int wi = colg0 >> 6;
    int d = (colg0 & 63) + lr;
    // fold 1/sqrt(H)*log2(e) into q so attn softmax uses 2^x directly
    float scale = (wi == 0) ? 0.18033688f : 1.0f;
#pragma unroll
    for (int r = 0; r < 4; r++) {
      int row = m0 + wr * 16 + g * 4 + r;
      int b = row >> 11, t = row & 2047;
      short bv = f2bf(acc[nf][r] * scale);
      if (wi == 0) {
        int idx = (((b * 128 + (t >> 4)) * 2 + (d >> 5)) * 64 +
                   ((((d >> 3) & 3) << 4) | (t & 15))) * 8 + (d & 7);
        qb[idx] = bv;
      } else if (wi == 1) {
        int u = (b << 2) | (((t >> 4) & 1) << 1) | (d >> 5);
        int idx = (((t >> 5) * 64 + u) << 9) +
                  ((((((d >> 3) & 3) << 4)) | (t & 15)) << 3) + (d & 7);
        kvb[idx] = bv;
      } else {
        int u = 32 + (b << 2) + (d >> 4);
        int idx = (((t >> 5) * 64 + u) << 9) +
                  (((((t >> 2) & 3) << 4) | (d & 15)) << 3) + (((t >> 4) & 1) << 2) + (t & 3);
        kvb[idx] = bv;
      }
    }
  }
}

// ---------------- Kernel 2: pipelined fused attention ----------------
__device__ __forceinline__ void stage_step(const short* __restrict__ kvb,
                                           short* lds_buf, int w, int l, int W) {
#pragma unroll
  for (int i = 0; i < 8; i++) {
    int u = w * 8 + i;
    const short* src = kvb + (((size_t)W * 64 + u) << 9) + l * 8;
    gload16(src, lds_buf + u * 512);
  }
}

// 512 thr = 8 waves: tt = w>>1 (4 t-tiles of 16), dh = w&1 (d-half for PV).
// Block covers 64 t-rows x one 128-s chunk; 4 steps of 32 s.
__global__ __launch_bounds__(512, 2) void attn_kernel(
    const short* __restrict__ qb, const short* __restrict__ kvb,
    short* __restrict__ partial) {
  __shared__ __align__(16) short lds[2][64 * 512];  // 2 x 64KB ring
  const int tid = threadIdx.x;
  const int l = tid & 63, w = tid >> 6;
  const int tt = w >> 1, dh = w & 1;
  // XCD-aware decode (512 blocks): per-XCD set = qb 2MB + kvb slices < 4MB L2
  const int lin = blockIdx.x;
  const int sc = (lin & 7) * 2 + ((lin >> 3) & 1);  // 0..15
  const int tblk = lin >> 4;                        // 0..31
  const int tb16 = tblk * 4 + tt;                   // 0..127

  // Q hoisted: 16 x b128
  short8 qf[8][2];
#pragma unroll
  for (int b = 0; b < 8; b++)
#pragma unroll
    for (int ks = 0; ks < 2; ks++)
      qf[b][ks] = *(const short8*)&qb[(size_t)((b * 128 + tb16) * 2 + ks) * 512 + l * 8];

  f32x4 oacc[8][2];
#pragma unroll
  for (int b = 0; b < 8; b++)
#pragma unroll
    for (int n = 0; n < 2; n++) oacc[b][n] = (f32x4){0.f, 0.f, 0.f, 0.f};

  // prologue: stage window 0
  stage_step(kvb, &lds[0][0], w, l, sc * 4);

  for (int it = 0; it < 4; it++) {
    __syncthreads();  // vmcnt(0)+lgkmcnt(0)+barrier: drains step-old staging
                      // (free), publishes buf[it] to all waves, and makes
                      // buf[it^1] safe to overwrite.
    if (it + 1 < 4) stage_step(kvb, &lds[(it + 1) & 1][0], w, l, sc * 4 + it + 1);
    const short* ldsc = &lds[it & 1][0];

    uint2_t plo[8], phi[8];
#pragma unroll
    for (int sf = 0; sf < 2; sf++) {
      // QK^T 16-s half: S[b][r] at s = sc*128+it*32+sf*16+g*4+r, t = tb16*16+(l&15)
      f32x4 S[8];
      __builtin_amdgcn_s_setprio(1);
#pragma unroll
      for (int b = 0; b < 8; b++) {
        short8 kf0 = *(const short8*)&ldsc[(b * 4 + sf * 2 + 0) * 512 + l * 8];
        short8 kf1 = *(const short8*)&ldsc[(b * 4 + sf * 2 + 1) * 512 + l * 8];
        f32x4 s = (f32x4){0.f, 0.f, 0.f, 0.f};
        s = MFMA32(kf0, qf[b][0], s);
        s = MFMA32(kf1, qf[b][1], s);
        S[b] = s;
      }
      __builtin_amdgcn_s_setprio(0);
      // softmax over batch (elementwise across the 8 register sets)
#pragma unroll
      for (int r = 0; r < 4; r++) {
        float den = 0.f;
#pragma unroll
        for (int b = 0; b < 8; b++) {
          float e = __builtin_amdgcn_exp2f(S[b][r]);
          S[b][r] = e;
          den += e;
        }
        float inv = __builtin_amdgcn_rcpf(den);
#pragma unroll
        for (int b = 0; b < 8; b++) S[b][r] *= inv;
      }
      // pack this 16-s half of P
#pragma unroll
      for (int b = 0; b < 8; b++) {
        uint2_t pw;
        pw[0] = cvt_pk_bf16(S[b][0], S[b][1]);
        pw[1] = cvt_pk_bf16(S[b][2], S[b][3]);
        if (sf == 0) plo[b] = pw; else phi[b] = pw;
      }
    }
    // PV with k=32: A = V unit (16 d x 32 s, sigma-map), B = packed P
    __builtin_amdgcn_s_setprio(1);
#pragma unroll
    for (int b = 0; b < 8; b++) {
      uint4_t pu;
      pu[0] = plo[b][0]; pu[1] = plo[b][1]; pu[2] = phi[b][0]; pu[3] = phi[b][1];
      short8 pbv = __builtin_bit_cast(short8, pu);
      short8 vf0 = *(const short8*)&ldsc[(32 + b * 4 + dh * 2 + 0) * 512 + l * 8];
      short8 vf1 = *(const short8*)&ldsc[(32 + b * 4 + dh * 2 + 1) * 512 + l * 8];
      oacc[b][0] = MFMA32(vf0, pbv, oacc[b][0]);
      oacc[b][1] = MFMA32(vf1, pbv, oacc[b][1]);
    }
    __builtin_amdgcn_s_setprio(0);
  }

  // store bf16 partial fragment-major (uint2/lane, wave-contiguous 512B runs)
  uint2_t* pout = (uint2_t*)partial;
#pragma unroll
  for (int b = 0; b < 8; b++)
#pragma unroll
    for (int n = 0; n < 2; n++) {
      int df = dh * 2 + n;
      uint2_t pk;
      pk[0] = cvt_pk_bf16(oacc[b][n][0], oacc[b][n][1]);
      pk[1] = cvt_pk_bf16(oacc[b][n][2], oacc[b][n][3]);
      __builtin_nontemporal_store(
          pk, &pout[(size_t)(((sc * 8 + b) * 128 + tb16) * 4 + df) * 64 + l]);
    }
}

// ---------------- Kernel 3: reduce bf16 partials -> f32 out ----------------
__global__ __launch_bounds__(256) void reduce_kernel(const short* __restrict__ partial,
                                                     float* __restrict__ out) {
  int i = blockIdx.x * 256 + threadIdx.x;  // 0..262143: (b,tb16,df,l)
  const uint2_t* p = (const uint2_t*)partial;
  float4_t a = (float4_t){0.f, 0.f, 0.f, 0.f};
  for (int sc = 0; sc < 16; sc++) {
    uint2_t v = __builtin_nontemporal_load(&p[(size_t)sc * 262144 + i]);
    a[0] += __builtin_bit_cast(float, v[0] << 16);
    a[1] += __builtin_bit_cast(float, v[0] & 0xFFFF0000u);
    a[2] += __builtin_bit_cast(float, v[1] << 16);
    a[3] += __builtin_bit_cast(float, v[1] & 0xFFFF0000u);
  }
  int b = i >> 15;
  int r1 = i & 32767;
  int tb16 = r1 >> 8;
  int r2 = r1 & 255;
  int df = r2 >> 6;
  int ll = r2 & 63;
  int gg = ll >> 4, lrr = ll & 15;
  *(float4_t*)&out[(size_t)(b * 2048 + tb16 * 16 + lrr) * 64 + df * 16 + gg * 4] = a;
}

extern "C" void kernel_launch(void* const* d_in, const int* in_sizes, int n_in,
                              void* d_out, int out_size, void* d_ws, size_t ws_size,
                              hipStream_t stream) {
  const float* x = (const float*)d_in[0];
  const float* Wq = (const float*)d_in[1];
  const float* Wk = (const float*)d_in[2];
  const float* Wv = (const float*)d_in[3];
  float* out = (float*)d_out;

  char* ws = (char*)d_ws;
  short* qb = (short*)ws;                     // 2MB
  short* kvb = qb + 16384 * 64;               // 4MB (64 windows x 64 units)
  short* partial = kvb + 2 * 16384 * 64;      // 33.5MB bf16 fragment-major
  short* Wtb = partial + 16ull * 262144 * 4;  // 384KB

  wprep_kernel<<<96, 256, 0, stream>>>(Wq, Wk, Wv, Wtb);
  proj_kernel<<<256, 512, 0, stream>>>(x, Wtb, qb, kvb);
  attn_kernel<<<512, 512, 0, stream>>>(qb, kvb, partial);
  reduce_kernel<<<1024, 256, 0, stream>>>(partial, out);
}

// Round 8
// 62.674 us; speedup vs baseline: 1.7091x; 1.4484x over previous
//
#include <hip/hip_runtime.h>
#include <hip/hip_bf16.h>

// B=8, T=2048, E=1024, H=64
// Round 8: proj rebuilt as counted-vmcnt ring-3 pipeline with fragment-major
// global_load_lds staging (x staged as f32 units, converted to bf16 at
// fragment-read time; W staged from pre-transposed bf16 Wtb). One barrier
// per K-tile, vmcnt(10) counted (2 tiles in flight). attn: 8 s-chunks
// (grid 256 = one pass/CU), partial halves to 16MB.
//
// Workspace: qb 2MB | kvb 4MB | partial 16MB | Wtb 384KB

typedef __attribute__((ext_vector_type(4))) float f32x4;
typedef __attribute__((ext_vector_type(4))) float float4_t;
typedef __attribute__((ext_vector_type(8))) short short8;
typedef __attribute__((ext_vector_type(4))) unsigned uint4_t;
typedef __attribute__((ext_vector_type(2))) unsigned uint2_t;

#define MFMA32(a, b, c) __builtin_amdgcn_mfma_f32_16x16x32_bf16(a, b, c, 0, 0, 0)

__device__ __forceinline__ short f2bf(float f) {
  unsigned u = __builtin_bit_cast(unsigned, f);
  unsigned r = (u + 0x7FFFu + ((u >> 16) & 1u)) >> 16;  // RNE
  return (short)r;
}

__device__ __forceinline__ unsigned cvt_pk_bf16(float lo, float hi) {
  unsigned r;
  asm volatile("v_cvt_pk_bf16_f32 %0, %1, %2" : "=v"(r) : "v"(lo), "v"(hi));
  return r;  // low16=bf16(lo), high16=bf16(hi)
}

__device__ __forceinline__ void gload16(const short* g, short* l) {
  __builtin_amdgcn_global_load_lds(
      (const __attribute__((address_space(1))) unsigned*)g,
      (__attribute__((address_space(3))) unsigned*)l, 16, 0, 0);
}

// ---------------- Kernel 0: W transpose+convert ----------------
// Wtb[n_global][k] bf16, n_global = wi*64 + n in [0,192), k in [0,1024)
__global__ __launch_bounds__(256) void wprep_kernel(
    const float* __restrict__ Wq, const float* __restrict__ Wk,
    const float* __restrict__ Wv, short* __restrict__ Wtb) {
  int lin = blockIdx.x * 256 + threadIdx.x;  // 24576 threads
  int n = lin & 63;
  int k8 = (lin >> 6) & 127;
  int wi = lin >> 13;
  const float* W = (wi == 0) ? Wq : (wi == 1) ? Wk : Wv;
  short* dst = Wtb + wi * 65536 + n * 1024 + k8 * 8;
#pragma unroll
  for (int i = 0; i < 8; i++) dst[i] = f2bf(W[(k8 * 8 + i) * 64 + n]);
}

// ---------------- Kernel 1: pipelined QKV projection ----------------
// 256 blocks x 256 thr (4 waves). M=64 rows/block, K-tiles of 64, ring-3.
// LDS tile = 40 units x 1KB: u<16 x-units (u = wr*4+ks*2+h, f32; lane l
// holds x[m0+wr*16+(l&15)][k0+32ks+8(l>>4)+4h .. +3]); u>=16 W-units
// (u = 16+nf*2+ks, bf16; lane l holds Wtb[nf*16+(l&15)][k0+32ks+8(l>>4)..+7]).
// Both operand fragments use the same k-bijection -> contraction exact.
__device__ __forceinline__ void proj_stage(const float* __restrict__ x,
                                           const short* __restrict__ Wtb,
                                           short* dst, int m0, int k0, int w, int l) {
  const int g = l >> 4, lr = l & 15;
#pragma unroll
  for (int i = 0; i < 10; i++) {
    int u = w * 10 + i;
    if (u < 16) {
      int wr = u >> 2, ks = (u >> 1) & 1, h = u & 1;
      const float* src = x + (size_t)(m0 + wr * 16 + lr) * 1024 + k0 + ks * 32 + g * 8 + h * 4;
      gload16((const short*)src, dst + u * 512);
    } else {
      int uu = u - 16, nf = uu >> 1, ks = uu & 1;
      const short* src = Wtb + (nf * 16 + lr) * 1024 + k0 + ks * 32 + g * 8;
      gload16(src, dst + u * 512);
    }
  }
}

__device__ __forceinline__ void proj_compute(const short* __restrict__ ldsb,
                                             f32x4 (&acc)[12], int w, int l) {
  short8 a[2];
#pragma unroll
  for (int ks = 0; ks < 2; ks++) {
    f32x4 fa = *(const f32x4*)&ldsb[(w * 4 + ks * 2 + 0) * 512 + l * 8];
    f32x4 fb = *(const f32x4*)&ldsb[(w * 4 + ks * 2 + 1) * 512 + l * 8];
    uint4_t u_;
    u_[0] = cvt_pk_bf16(fa[0], fa[1]);
    u_[1] = cvt_pk_bf16(fa[2], fa[3]);
    u_[2] = cvt_pk_bf16(fb[0], fb[1]);
    u_[3] = cvt_pk_bf16(fb[2], fb[3]);
    a[ks] = __builtin_bit_cast(short8, u_);
  }
#pragma unroll
  for (int nf = 0; nf < 12; nf++) {
#pragma unroll
    for (int ks = 0; ks < 2; ks++) {
      short8 bfrag = *(const short8*)&ldsb[(16 + nf * 2 + ks) * 512 + l * 8];
      acc[nf] = MFMA32(a[ks], bfrag, acc[nf]);
    }
  }
}

template <int I>
__device__ __forceinline__ void proj_step(const float* __restrict__ x,
                                          const short* __restrict__ Wtb, short* lds,
                                          f32x4 (&acc)[12], int m0, int w, int l) {
  // outstanding at top: tiles {I (10), I+1 (10 if exists)} -> vmcnt(10) waits
  // tile I; never 0 mid-loop.
  constexpr int NW = (I == 15) ? 0 : 10;
  __builtin_amdgcn_sched_barrier(0);
  asm volatile("s_waitcnt vmcnt(%0) lgkmcnt(0)" ::"n"(NW) : "memory");
  __builtin_amdgcn_s_barrier();
  __builtin_amdgcn_sched_barrier(0);
  if constexpr (I + 2 < 16)
    proj_stage(x, Wtb, lds + ((I + 2) % 3) * 20480, m0, (I + 2) * 64, w, l);
  proj_compute(lds + (I % 3) * 20480, acc, w, l);
}

__global__ __launch_bounds__(256) void proj_kernel(
    const float* __restrict__ x, const short* __restrict__ Wtb,
    short* __restrict__ qb, short* __restrict__ kvb) {
  __shared__ __align__(16) short lds[3 * 40 * 512];  // 120KB
  const int tid = threadIdx.x;
  const int l = tid & 63, w = tid >> 6;
  const int g = l >> 4, lr = l & 15;
  const int m0 = blockIdx.x * 64;

  f32x4 acc[12];
#pragma unroll
  for (int i = 0; i < 12; i++) acc[i] = (f32x4){0.f, 0.f, 0.f, 0.f};

  proj_stage(x, Wtb, lds, m0, 0, w, l);
  proj_stage(x, Wtb, lds + 20480, m0, 64, w, l);

  proj_step<0>(x, Wtb, lds, acc, m0, w, l);
  proj_step<1>(x, Wtb, lds, acc, m0, w, l);
  proj_step<2>(x, Wtb, lds, acc, m0, w, l);
  proj_step<3>(x, Wtb, lds, acc, m0, w, l);
  proj_step<4>(x, Wtb, lds, acc, m0, w, l);
  proj_step<5>(x, Wtb, lds, acc, m0, w, l);
  proj_step<6>(x, Wtb, lds, acc, m0, w, l);
  proj_step<7>(x, Wtb, lds, acc, m0, w, l);
  proj_step<8>(x, Wtb, lds, acc, m0, w, l);
  proj_step<9>(x, Wtb, lds, acc, m0, w, l);
  proj_step<10>(x, Wtb, lds, acc, m0, w, l);
  proj_step<11>(x, Wtb, lds, acc, m0, w, l);
  proj_step<12>(x, Wtb, lds, acc, m0, w, l);
  proj_step<13>(x, Wtb, lds, acc, m0, w, l);
  proj_step<14>(x, Wtb, lds, acc, m0, w, l);
  proj_step<15>(x, Wtb, lds, acc, m0, w, l);

  // epilogue: same verified store formulas (wave w = 16 rows, all 192 cols)
#pragma unroll
  for (int nf = 0; nf < 12; nf++) {
    int colg0 = nf * 16;
    int wi = colg0 >> 6;
    int d = (colg0 & 63) + lr;
    // fold 1/sqrt(H)*log2(e) into q so attn softmax uses 2^x directly
    float scale = (wi == 0) ? 0.18033688f : 1.0f;
#pragma unroll
    for (int r = 0; r < 4; r++) {
      int row = m0 + w * 16 + g * 4 + r;
      int b = row >> 11, t = row & 2047;
      short bv = f2bf(acc[nf][r] * scale);
      if (wi == 0) {
        int idx = (((b * 128 + (t >> 4)) * 2 + (d >> 5)) * 64 +
                   ((((d >> 3) & 3) << 4) | (t & 15))) * 8 + (d & 7);
        qb[idx] = bv;
      } else if (wi == 1) {
        int u = (b << 2) | (((t >> 4) & 1) << 1) | (d >> 5);
        int idx = (((t >> 5) * 64 + u) << 9) +
                  ((((((d >> 3) & 3) << 4)) | (t & 15)) << 3) + (d & 7);
        kvb[idx] = bv;
      } else {
        int u = 32 + (b << 2) + (d >> 4);
        int idx = (((t >> 5) * 64 + u) << 9) +
                  (((((t >> 2) & 3) << 4) | (d & 15)) << 3) + (((t >> 4) & 1) << 2) + (t & 3);
        kvb[idx] = bv;
      }
    }
  }
}

// ---------------- Kernel 2: pipelined fused attention ----------------
__device__ __forceinline__ void stage_step(const short* __restrict__ kvb,
                                           short* lds_buf, int w, int l, int W) {
#pragma unroll
  for (int i = 0; i < 8; i++) {
    int u = w * 8 + i;
    const short* src = kvb + (((size_t)W * 64 + u) << 9) + l * 8;
    gload16(src, lds_buf + u * 512);
  }
}

// 256 blocks x 512 thr = 8 waves: tt = w>>1 (4 t-tiles of 16), dh = w&1.
// Block: 64 t-rows x one 256-s chunk; 8 steps of 32 s. sc = xcd (lin&7).
__global__ __launch_bounds__(512, 2) void attn_kernel(
    const short* __restrict__ qb, const short* __restrict__ kvb,
    short* __restrict__ partial) {
  __shared__ __align__(16) short lds[2][64 * 512];  // 2 x 64KB ring
  const int tid = threadIdx.x;
  const int l = tid & 63, w = tid >> 6;
  const int tt = w >> 1, dh = w & 1;
  const int lin = blockIdx.x;     // 0..255
  const int sc = lin & 7;         // 0..7: per-XCD s-chunk of 256
  const int tblk = lin >> 3;      // 0..31
  const int tb16 = tblk * 4 + tt; // 0..127

  // Q hoisted: 16 x b128
  short8 qf[8][2];
#pragma unroll
  for (int b = 0; b < 8; b++)
#pragma unroll
    for (int ks = 0; ks < 2; ks++)
      qf[b][ks] = *(const short8*)&qb[(size_t)((b * 128 + tb16) * 2 + ks) * 512 + l * 8];

  f32x4 oacc[8][2];
#pragma unroll
  for (int b = 0; b < 8; b++)
#pragma unroll
    for (int n = 0; n < 2; n++) oacc[b][n] = (f32x4){0.f, 0.f, 0.f, 0.f};

  stage_step(kvb, &lds[0][0], w, l, sc * 8);

  for (int it = 0; it < 8; it++) {
    __syncthreads();  // drains step-old staging (free), publishes buf[it]
    if (it + 1 < 8) stage_step(kvb, &lds[(it + 1) & 1][0], w, l, sc * 8 + it + 1);
    const short* ldsc = &lds[it & 1][0];

    uint2_t plo[8], phi[8];
#pragma unroll
    for (int sf = 0; sf < 2; sf++) {
      f32x4 S[8];
      __builtin_amdgcn_s_setprio(1);
#pragma unroll
      for (int b = 0; b < 8; b++) {
        short8 kf0 = *(const short8*)&ldsc[(b * 4 + sf * 2 + 0) * 512 + l * 8];
        short8 kf1 = *(const short8*)&ldsc[(b * 4 + sf * 2 + 1) * 512 + l * 8];
        f32x4 s = (f32x4){0.f, 0.f, 0.f, 0.f};
        s = MFMA32(kf0, qf[b][0], s);
        s = MFMA32(kf1, qf[b][1], s);
        S[b] = s;
      }
      __builtin_amdgcn_s_setprio(0);
      // softmax over batch (elementwise across the 8 register sets)
#pragma unroll
      for (int r = 0; r < 4; r++) {
        float den = 0.f;
#pragma unroll
        for (int b = 0; b < 8; b++) {
          float e = __builtin_amdgcn_exp2f(S[b][r]);
          S[b][r] = e;
          den += e;
        }
        float inv = __builtin_amdgcn_rcpf(den);
#pragma unroll
        for (int b = 0; b < 8; b++) S[b][r] *= inv;
      }
#pragma unroll
      for (int b = 0; b < 8; b++) {
        uint2_t pw;
        pw[0] = cvt_pk_bf16(S[b][0], S[b][1]);
        pw[1] = cvt_pk_bf16(S[b][2], S[b][3]);
        if (sf == 0) plo[b] = pw; else phi[b] = pw;
      }
    }
    // PV k=32: A = V unit (16 d x 32 s, sigma-map), B = packed P
    __builtin_amdgcn_s_setprio(1);
#pragma unroll
    for (int b = 0; b < 8; b++) {
      uint4_t pu;
      pu[0] = plo[b][0]; pu[1] = plo[b][1]; pu[2] = phi[b][0]; pu[3] = phi[b][1];
      short8 pbv = __builtin_bit_cast(short8, pu);
      short8 vf0 = *(const short8*)&ldsc[(32 + b * 4 + dh * 2 + 0) * 512 + l * 8];
      short8 vf1 = *(const short8*)&ldsc[(32 + b * 4 + dh * 2 + 1) * 512 + l * 8];
      oacc[b][0] = MFMA32(vf0, pbv, oacc[b][0]);
      oacc[b][1] = MFMA32(vf1, pbv, oacc[b][1]);
    }
    __builtin_amdgcn_s_setprio(0);
  }

  // store bf16 partial fragment-major (uint2/lane, wave-contiguous 512B runs)
  uint2_t* pout = (uint2_t*)partial;
#pragma unroll
  for (int b = 0; b < 8; b++)
#pragma unroll
    for (int n = 0; n < 2; n++) {
      int df = dh * 2 + n;
      uint2_t pk;
      pk[0] = cvt_pk_bf16(oacc[b][n][0], oacc[b][n][1]);
      pk[1] = cvt_pk_bf16(oacc[b][n][2], oacc[b][n][3]);
      __builtin_nontemporal_store(
          pk, &pout[(size_t)(((sc * 8 + b) * 128 + tb16) * 4 + df) * 64 + l]);
    }
}

// ---------------- Kernel 3: reduce bf16 partials -> f32 out ----------------
__global__ __launch_bounds__(256) void reduce_kernel(const short* __restrict__ partial,
                                                     float* __restrict__ out) {
  int i = blockIdx.x * 256 + threadIdx.x;  // 0..262143: (b,tb16,df,l)
  const uint2_t* p = (const uint2_t*)partial;
  float4_t a = (float4_t){0.f, 0.f, 0.f, 0.f};
  for (int sc = 0; sc < 8; sc++) {
    uint2_t v = __builtin_nontemporal_load(&p[(size_t)sc * 262144 + i]);
    a[0] += __builtin_bit_cast(float, v[0] << 16);
    a[1] += __builtin_bit_cast(float, v[0] & 0xFFFF0000u);
    a[2] += __builtin_bit_cast(float, v[1] << 16);
    a[3] += __builtin_bit_cast(float, v[1] & 0xFFFF0000u);
  }
  int b = i >> 15;
  int r1 = i & 32767;
  int tb16 = r1 >> 8;
  int r2 = r1 & 255;
  int df = r2 >> 6;
  int ll = r2 & 63;
  int gg = ll >> 4, lrr = ll & 15;
  *(float4_t*)&out[(size_t)(b * 2048 + tb16 * 16 + lrr) * 64 + df * 16 + gg * 4] = a;
}

extern "C" void kernel_launch(void* const* d_in, const int* in_sizes, int n_in,
                              void* d_out, int out_size, void* d_ws, size_t ws_size,
                              hipStream_t stream) {
  const float* x = (const float*)d_in[0];
  const float* Wq = (const float*)d_in[1];
  const float* Wk = (const float*)d_in[2];
  const float* Wv = (const float*)d_in[3];
  float* out = (float*)d_out;

  char* ws = (char*)d_ws;
  short* qb = (short*)ws;                     // 2MB
  short* kvb = qb + 16384 * 64;               // 4MB (64 windows x 64 units)
  short* partial = kvb + 2 * 16384 * 64;      // 16MB bf16 fragment-major
  short* Wtb = partial + 8ull * 262144 * 4;   // 384KB

  wprep_kernel<<<96, 256, 0, stream>>>(Wq, Wk, Wv, Wtb);
  proj_kernel<<<256, 256, 0, stream>>>(x, Wtb, qb, kvb);
  attn_kernel<<<256, 512, 0, stream>>>(qb, kvb, partial);
  reduce_kernel<<<1024, 256, 0, stream>>>(partial, out);
}